// Round 8
// baseline (78.855 us; speedup 1.0000x reference)
//
#include <hip/hip_runtime.h>
#include <hip/hip_bf16.h>

// FastCapsNetMulti via bf16 MFMA, 4 launches:
//  k1 prep: blocks 0..179    wh   -> wtb2[tap][cb20][oc32][8] bf16
//           blocks 180..2355 x_hsi-> xb2[b][cb20][y34][x34][8] bf16 (zero-padded,
//                            LDS-transposed for coalesced global reads)
//           block  2356      wsar -> wt_s[cin][tap][oc] fp32
//  k2 conv_both: blocks 0..511    HSI conv: stage 6 padded rows (65KB LDS, pure
//                                 bf16 copy) -> 45 MFMA iters with 9x tap reuse
//                blocks 512..767  SAR conv (fp32 VALU, thread=pixel)
//                both -> squash -> capsb[b][n][8] bf16
//  k3 routing: s[b,cj] = sum caps*W; 32-n chunks LDS-transposed, W fp32->bf16 inline
//  k4 finalize: reduce + squash + |v|
// B=64, H=W=32, N=8192, classes=10, class_dim=16, cap_dim=8.

typedef __attribute__((ext_vector_type(8))) short bf16x8s;
typedef __attribute__((ext_vector_type(4))) float f32x4;

__device__ inline short f2bf(float f) {
    __hip_bfloat16 h = __float2bfloat16(f);
    return *reinterpret_cast<short*>(&h);
}

#define XPLANE 1156            // 34*34 pixels per cb plane
#define XB_B (20 * XPLANE * 8) // elements per b in xb2

// ---------------- k1: prep ---------------------------------------------------
__global__ __launch_bounds__(256) void prep_kernel(
        const float* __restrict__ wh, short* __restrict__ wtb2,
        const float* __restrict__ x_hsi, short* __restrict__ xb2,
        const float* __restrict__ wsar, float* __restrict__ wt_s) {
    __shared__ short tile[144][33];
    int t = threadIdx.x;
    if (blockIdx.x < 180) {
        // wtb2[tap][cb][oc][d]
        int idx = blockIdx.x * 256 + t;       // < 9*20*32*8 = 46080
        int tap = idx / 5120;
        int r2 = idx - tap * 5120;
        int cb = r2 >> 8;
        int oc = (r2 >> 3) & 31;
        int d = r2 & 7;
        int ch = cb * 8 + d;
        short v = 0;
        if (ch < 144) v = f2bf(wh[(oc * 144 + ch) * 9 + tap]);
        wtb2[idx] = v;
        return;
    }
    if (blockIdx.x == 2356) {                 // SAR weight transpose
        for (int idx = t; idx < 1152; idx += 256) {
            int oc = idx & 31;
            int rest = idx >> 5;
            int tap = rest % 9;
            int cin = rest / 9;
            wt_s[cin * 288 + tap * 32 + oc] = wsar[(oc * 4 + cin) * 9 + tap];
        }
        return;
    }
    // xb2: one block per (b, padded row y_o); coalesced reads via LDS transpose
    int blk = blockIdx.x - 180;               // 0..2175
    int b = blk / 34;
    int y_o = blk - b * 34;
    bool yok = (y_o >= 1) && (y_o <= 32);
    int iy = y_o - 1;
    if (yok) {
        for (int base = 0; base < 144; base += 8) {
            int ch = base + (t >> 5), x = t & 31;
            tile[ch][x] = f2bf(x_hsi[(((size_t)b * 144 + ch) * 32 + iy) * 32 + x]);
        }
    }
    __syncthreads();
    short* dstb = xb2 + (size_t)b * XB_B;
    for (int item = t; item < 680; item += 256) {   // 20 cb x 34 xx, 16B each
        int cb = item / 34;
        int xx = item - cb * 34;
        bf16x8s v = {0, 0, 0, 0, 0, 0, 0, 0};
        if (yok && xx >= 1 && xx <= 32 && cb < 18) {
            int x = xx - 1;
            #pragma unroll
            for (int d = 0; d < 8; ++d) v[d] = tile[cb * 8 + d][x];
        }
        *(bf16x8s*)(dstb + ((size_t)(cb * 34 + y_o) * 34 + xx) * 8) = v;
    }
}

// ---------------- k2: fused conv (HSI MFMA + SAR VALU) -----------------------
// HSI: blocks 0..511 = b(64) x ytile(8, 4 output rows). Stage padded rows
// y0..y0+5 x 34x x 160ch bf16 (65280B LDS) as a straight coalesced copy from
// xb2; then 4 waves (wave = output row) x 2 x-halves x 2 oc-tiles, A from LDS
// (9-tap reuse), B from L1-hot wtb2. C via LDS -> squash -> capsb.
// SAR: blocks 512..767, thread = 1 pixel, all 4 cin x 32 oc, uniform weights.
__global__ __launch_bounds__(256) void conv_both_kernel(
        const float* __restrict__ x_sar, const short* __restrict__ xb2,
        const short* __restrict__ wtb2, const float* __restrict__ bh,
        const float* __restrict__ wt_s, const float* __restrict__ bs,
        short* __restrict__ capsb) {
    __shared__ union {
        short xs[20][6][34][8];   // [cb][row][xx][d] = 65280 B
        float ct[128][33];        // C-tile for epilogue = 16896 B
    } sm;
    int t = threadIdx.x;

    if (blockIdx.x < 512) {
        int b = blockIdx.x >> 3;
        int y0 = (blockIdx.x & 7) << 2;       // output rows y0..y0+3

        // ---- stage: pure bf16 copy, coalesced 16B/lane ----------------------
        const short* src = xb2 + (size_t)b * XB_B;
        for (int i = t; i < 4080; i += 256) {  // 20*6*34 16B items
            int cb = i / 204;
            int rem = i - cb * 204;
            int row = rem / 34;
            int xx = rem - row * 34;
            bf16x8s v = *(const bf16x8s*)(src + ((size_t)(cb * 34 + y0 + row) * 34 + xx) * 8);
            *(bf16x8s*)&sm.xs[cb][row][xx][0] = v;
        }
        __syncthreads();

        int l = t & 63;
        int wv = t >> 6;                      // wave = output row y0+wv
        int l15 = l & 15, lhi = l >> 4;

        f32x4 acc[2][2] = {{{0.f,0.f,0.f,0.f},{0.f,0.f,0.f,0.f}},
                           {{0.f,0.f,0.f,0.f},{0.f,0.f,0.f,0.f}}};

        #pragma unroll
        for (int tap = 0; tap < 9; ++tap) {
            int dy = tap / 3, dx = tap % 3;
            #pragma unroll
            for (int kc = 0; kc < 5; ++kc) {
                bf16x8s a0 = *(const bf16x8s*)&sm.xs[kc * 4 + lhi][wv + dy][l15 + dx][0];
                bf16x8s a1 = *(const bf16x8s*)&sm.xs[kc * 4 + lhi][wv + dy][16 + l15 + dx][0];
                const short* wa = wtb2 + ((size_t)(tap * 20 + kc * 4 + lhi) * 32 + l15) * 8;
                bf16x8s b0 = *(const bf16x8s*)wa;
                bf16x8s b1 = *(const bf16x8s*)(wa + 128);   // +16 oc
                acc[0][0] = __builtin_amdgcn_mfma_f32_16x16x32_bf16(a0, b0, acc[0][0], 0, 0, 0);
                acc[0][1] = __builtin_amdgcn_mfma_f32_16x16x32_bf16(a0, b1, acc[0][1], 0, 0, 0);
                acc[1][0] = __builtin_amdgcn_mfma_f32_16x16x32_bf16(a1, b0, acc[1][0], 0, 0, 0);
                acc[1][1] = __builtin_amdgcn_mfma_f32_16x16x32_bf16(a1, b1, acc[1][1], 0, 0, 0);
            }
        }
        __syncthreads();   // xs reads done before ct overwrites

        #pragma unroll
        for (int xh = 0; xh < 2; ++xh)
            #pragma unroll
            for (int nt = 0; nt < 2; ++nt)
                #pragma unroll
                for (int r = 0; r < 4; ++r)
                    sm.ct[wv * 32 + xh * 16 + lhi * 4 + r][nt * 16 + l15] = acc[xh][nt][r];
        __syncthreads();

        // ---- epilogue: 512 capsules (128 px x 4 caps) -----------------------
        #pragma unroll
        for (int h = 0; h < 2; ++h) {
            int q = t + h * 256;
            int p = q >> 2;          // local pixel 0..127
            int cap = q & 3;
            float s[8];
            float sq = 0.0f;
            #pragma unroll
            for (int d = 0; d < 8; ++d) {
                s[d] = sm.ct[p][cap * 8 + d] + bh[cap * 8 + d];
                sq += s[d] * s[d];
            }
            float scale = sq / ((1.0f + sq) * sqrtf(sq + 1e-8f));
            int pix = (y0 + (p >> 5)) * 32 + (p & 31);
            int n = pix * 4 + cap;
            bf16x8s o;
            #pragma unroll
            for (int d = 0; d < 8; ++d) o[d] = f2bf(s[d] * scale);
            *(bf16x8s*)(capsb + ((size_t)b * 8192 + n) * 8) = o;
        }
    } else {
        // ---- SAR: thread = 1 pixel, all cin, all oc; uniform scalar weights -
        int px_global = (blockIdx.x - 512) * 256 + t;    // 0..65535
        int b = px_global >> 10;
        int p = px_global & 1023;
        int y = p >> 5, x = p & 31;

        float acc[32];
        #pragma unroll
        for (int oc = 0; oc < 32; ++oc) acc[oc] = bs[oc];

        for (int cin = 0; cin < 4; ++cin) {
            const float* xc = x_sar + ((size_t)b * 4 + cin) * 1024;
            const float* wc = wt_s + cin * 288;
            #pragma unroll
            for (int ky = 0; ky < 3; ++ky) {
                int iy = y + ky - 1;
                bool rowok = (iy >= 0) && (iy < 32);
                const float* xrow = xc + iy * 32;
                float v0 = (rowok && x > 0)  ? xrow[x - 1] : 0.0f;
                float v1 = rowok             ? xrow[x]     : 0.0f;
                float v2 = (rowok && x < 31) ? xrow[x + 1] : 0.0f;
                const float* wk = wc + ky * 96;
                #pragma unroll
                for (int oc = 0; oc < 32; ++oc)
                    acc[oc] += v0 * wk[oc] + v1 * wk[32 + oc] + v2 * wk[64 + oc];
            }
        }

        #pragma unroll
        for (int cap = 0; cap < 4; ++cap) {
            float sq = 0.0f;
            #pragma unroll
            for (int d = 0; d < 8; ++d) sq += acc[cap * 8 + d] * acc[cap * 8 + d];
            float scale = sq / ((1.0f + sq) * sqrtf(sq + 1e-8f));
            int n = 4096 + p * 4 + cap;
            bf16x8s o;
            #pragma unroll
            for (int d = 0; d < 8; ++d) o[d] = f2bf(acc[cap * 8 + d] * scale);
            *(bf16x8s*)(capsb + ((size_t)b * 8192 + n) * 8) = o;
        }
    }
}

// ---------------- k3: routing via MFMA ---------------------------------------
// grid (kc 256) x (ntp 5). Block: stage caps[b][kc*32 .. +32] -> LDS [n][b][8]
// (transpose on write), 8 K-steps (2 per wave), 2 cj-tiles per block.
__global__ __launch_bounds__(256) void routing_mfma_kernel(
        const short* __restrict__ capsb, const float* __restrict__ W,
        float* __restrict__ partials) {
    __shared__ union {
        short ct[32][64][8];    // [n_local][b][8] = 32768 B
        float red[4][64][32];   // cross-wave reduce = 32768 B
    } sm;
    int t = threadIdx.x;
    int kc = blockIdx.x;
    int ntp = blockIdx.y;
    int n0 = kc * 32;

    {   // stage: thread t: b = t>>2, ng = t&3; 8x contiguous 16B global reads
        int b = t >> 2;
        int ng = t & 3;
        const short* src = capsb + ((size_t)b * 8192 + n0 + ng * 8) * 8;
        #pragma unroll
        for (int i = 0; i < 8; ++i) {
            bf16x8s v = *(const bf16x8s*)(src + i * 8);
            *(bf16x8s*)&sm.ct[ng * 8 + i][b][0] = v;
        }
    }
    __syncthreads();

    int l = t & 63;
    int wv = t >> 6;
    int l15 = l & 15, lhi = l >> 4;

    f32x4 acc[2][4];
    #pragma unroll
    for (int a = 0; a < 2; ++a)
        #pragma unroll
        for (int m = 0; m < 4; ++m) acc[a][m] = (f32x4){0.f, 0.f, 0.f, 0.f};

    #pragma unroll
    for (int ks = 0; ks < 2; ++ks) {
        int nl = (wv * 2 + ks) * 4 + lhi;     // n_local 0..31
        int n = n0 + nl;
        const float* wp = W + ((size_t)n * 160 + ntp * 32 + l15) * 8;
        union { short s[8]; bf16x8s v; } bu[2];
        #pragma unroll
        for (int ntl = 0; ntl < 2; ++ntl) {
            const float* wq = wp + (size_t)ntl * 128;   // +16 cj
            float4 w0 = *(const float4*)wq;
            float4 w1 = *(const float4*)(wq + 4);
            bu[ntl].s[0] = f2bf(w0.x); bu[ntl].s[1] = f2bf(w0.y);
            bu[ntl].s[2] = f2bf(w0.z); bu[ntl].s[3] = f2bf(w0.w);
            bu[ntl].s[4] = f2bf(w1.x); bu[ntl].s[5] = f2bf(w1.y);
            bu[ntl].s[6] = f2bf(w1.z); bu[ntl].s[7] = f2bf(w1.w);
        }
        bf16x8s af[4];
        #pragma unroll
        for (int mt = 0; mt < 4; ++mt)
            af[mt] = *(const bf16x8s*)&sm.ct[nl][mt * 16 + l15][0];
        #pragma unroll
        for (int ntl = 0; ntl < 2; ++ntl)
            #pragma unroll
            for (int mt = 0; mt < 4; ++mt)
                acc[ntl][mt] = __builtin_amdgcn_mfma_f32_16x16x32_bf16(
                    af[mt], bu[ntl].v, acc[ntl][mt], 0, 0, 0);
    }
    __syncthreads();   // all ct reads done before red overwrites

    #pragma unroll
    for (int ntl = 0; ntl < 2; ++ntl)
        #pragma unroll
        for (int mt = 0; mt < 4; ++mt)
            #pragma unroll
            for (int r = 0; r < 4; ++r)
                sm.red[wv][mt * 16 + lhi * 4 + r][ntl * 16 + l15] = acc[ntl][mt][r];
    __syncthreads();

    for (int idx = t; idx < 2048; idx += 256) {
        int b = idx >> 5, cjl = idx & 31;
        float sum = sm.red[0][b][cjl] + sm.red[1][b][cjl]
                  + sm.red[2][b][cjl] + sm.red[3][b][cjl];
        partials[(((size_t)kc * 5 + ntp) * 64 + b) * 32 + cjl] = sum;
    }
}

// ---------------- k4: final reduce + squash + norm ---------------------------
__global__ __launch_bounds__(256) void finalize_kernel(
        const float* __restrict__ partials, float* __restrict__ out) {
    __shared__ float s_sh[160];
    int t = threadIdx.x;
    int b = blockIdx.x;
    if (t < 160) {
        int ntp = t >> 5, cjl = t & 31;
        float s = 0.0f;
        #pragma unroll 8
        for (int kc = 0; kc < 256; ++kc)
            s += partials[(((size_t)kc * 5 + ntp) * 64 + b) * 32 + cjl];
        s_sh[ntp * 32 + cjl] = s * (1.0f / 8192.0f);
    }
    __syncthreads();
    if (t < 10) {
        float sq = 0.0f;
        #pragma unroll
        for (int j = 0; j < 16; ++j) {
            float v = s_sh[t * 16 + j];
            sq += v * v;
        }
        float scale = sq / ((1.0f + sq) * sqrtf(sq + 1e-8f));
        out[b * 10 + t] = sqrtf(sq) * scale;
    }
}

extern "C" void kernel_launch(void* const* d_in, const int* in_sizes, int n_in,
                              void* d_out, int out_size, void* d_ws, size_t ws_size,
                              hipStream_t stream) {
    const float* x_hsi = (const float*)d_in[0];   // [64,144,32,32]
    const float* x_sar = (const float*)d_in[1];   // [64,4,32,32]
    const float* wh    = (const float*)d_in[2];   // [32,144,3,3]
    const float* bh    = (const float*)d_in[3];   // [32]
    const float* wsar  = (const float*)d_in[4];   // [32,4,3,3]
    const float* bs    = (const float*)d_in[5];   // [32]
    const float* W     = (const float*)d_in[6];   // [8192,10,16,8]
    float* out = (float*)d_out;                   // [64,10]

    char* ws = (char*)d_ws;
    short* wtb2     = (short*)(ws + 0);           // 9*20*32*8*2 = 92160 B
    float* wt_s     = (float*)(ws + 98304);       // 4*9*32*4 = 4608 B
    short* xb2      = (short*)(ws + 131072);      // 64*20*34*34*8*2 = 23674880 B
    // partials aliases xb2 (xb2 dead once conv_both completes; same-stream order)
    float* partials = (float*)(ws + 131072);      // 256*5*64*32*4 = 10485760 B
    short* capsb    = (short*)(ws + 23805952);    // [64][8192][8] bf16 = 8388608 B

    prep_kernel<<<2357, 256, 0, stream>>>(wh, wtb2, x_hsi, xb2, wsar, wt_s);

    conv_both_kernel<<<768, 256, 0, stream>>>(x_sar, xb2, wtb2, bh, wt_s, bs, capsb);

    routing_mfma_kernel<<<dim3(256, 5), 256, 0, stream>>>(capsb, W, partials);

    finalize_kernel<<<64, 256, 0, stream>>>(partials, out);
}

// Round 9
// 76.809 us; speedup vs baseline: 1.0266x; 1.0266x over previous
//
#include <hip/hip_runtime.h>
#include <hip/hip_bf16.h>

// FastCapsNetMulti via bf16 MFMA, 4 launches:
//  k1 prep: blocks 0..179    wh   -> wtb2[tap][cb20][oc32][8] bf16
//           blocks 180..2355 x_hsi-> xb2[b][cb20][y34][x34][8] bf16 (zero-padded)
//           blocks 2356..2611 SAR conv (weights transposed to LDS, thread=pixel)
//  k2 conv_hsi: 1024 blocks = b(64) x ytile(16, 2 output rows). Stage 4 padded
//               rows into 43.6KB LDS (plane-padded -> conflict-free A reads),
//               45 MFMA steps with 9x tap reuse, squash -> capsb[b][n][8]
//  k3 routing: s[b,cj] = sum caps*W; 32-n chunks LDS-transposed, W fp32->bf16 inline
//  k4 finalize: reduce + squash + |v|
// B=64, H=W=32, N=8192, classes=10, class_dim=16, cap_dim=8.

typedef __attribute__((ext_vector_type(8))) short bf16x8s;
typedef __attribute__((ext_vector_type(4))) float f32x4;

__device__ inline short f2bf(float f) {
    __hip_bfloat16 h = __float2bfloat16(f);
    return *reinterpret_cast<short*>(&h);
}

#define XB_B (20 * 1156 * 8)   // elements per b in xb2 ([cb][34][34][8])
#define PLANE_SH 1090          // 136 items * 8 + 2-short pad -> stride ≡ 1 bank (mod 32)

// ---------------- k1: prep (weights + activations + SAR conv) ----------------
__global__ __launch_bounds__(256) void prep_kernel(
        const float* __restrict__ wh, short* __restrict__ wtb2,
        const float* __restrict__ x_hsi, short* __restrict__ xb2,
        const float* __restrict__ x_sar, const float* __restrict__ wsar,
        const float* __restrict__ bs, short* __restrict__ capsb) {
    __shared__ union {
        short tile[144][33];    // x-pass transpose
        float wt_lds[1152];     // SAR weights [cin][tap][oc]
    } sm;
    int t = threadIdx.x;

    if (blockIdx.x < 180) {
        // wtb2[tap][cb][oc][d]
        int idx = blockIdx.x * 256 + t;       // < 9*20*32*8 = 46080
        int tap = idx / 5120;
        int r2 = idx - tap * 5120;
        int cb = r2 >> 8;
        int oc = (r2 >> 3) & 31;
        int d = r2 & 7;
        int ch = cb * 8 + d;
        short v = 0;
        if (ch < 144) v = f2bf(wh[(oc * 144 + ch) * 9 + tap]);
        wtb2[idx] = v;
        return;
    }

    if (blockIdx.x >= 2356) {
        // ---- SAR conv: stage transposed weights to LDS, thread = 1 pixel ----
        for (int i = t; i < 1152; i += 256) {
            int oc = i / 36;
            int r = i - oc * 36;
            int cin = r / 9;
            int tap = r - cin * 9;
            sm.wt_lds[cin * 288 + tap * 32 + oc] = wsar[i];
        }
        __syncthreads();

        int px_global = (blockIdx.x - 2356) * 256 + t;   // 0..65535
        int b = px_global >> 10;
        int p = px_global & 1023;
        int y = p >> 5, x = p & 31;

        float acc[32];
        #pragma unroll
        for (int oc = 0; oc < 32; ++oc) acc[oc] = bs[oc];

        for (int cin = 0; cin < 4; ++cin) {
            const float* xc = x_sar + ((size_t)b * 4 + cin) * 1024;
            const float* wc = &sm.wt_lds[cin * 288];
            #pragma unroll
            for (int ky = 0; ky < 3; ++ky) {
                int iy = y + ky - 1;
                bool rowok = (iy >= 0) && (iy < 32);
                const float* xrow = xc + iy * 32;
                float v0 = (rowok && x > 0)  ? xrow[x - 1] : 0.0f;
                float v1 = rowok             ? xrow[x]     : 0.0f;
                float v2 = (rowok && x < 31) ? xrow[x + 1] : 0.0f;
                const float* wk = wc + ky * 96;
                #pragma unroll
                for (int oc = 0; oc < 32; ++oc)
                    acc[oc] += v0 * wk[oc] + v1 * wk[32 + oc] + v2 * wk[64 + oc];
            }
        }

        #pragma unroll
        for (int cap = 0; cap < 4; ++cap) {
            float sq = 0.0f;
            #pragma unroll
            for (int d = 0; d < 8; ++d) sq += acc[cap * 8 + d] * acc[cap * 8 + d];
            float scale = sq / ((1.0f + sq) * sqrtf(sq + 1e-8f));
            int n = 4096 + p * 4 + cap;
            bf16x8s o;
            #pragma unroll
            for (int d = 0; d < 8; ++d) o[d] = f2bf(acc[cap * 8 + d] * scale);
            *(bf16x8s*)(capsb + ((size_t)b * 8192 + n) * 8) = o;
        }
        return;
    }

    // ---- x-pass: one block per (b, padded row y_o); LDS transpose ----------
    int blk = blockIdx.x - 180;               // 0..2175
    int b = blk / 34;
    int y_o = blk - b * 34;
    bool yok = (y_o >= 1) && (y_o <= 32);
    int iy = y_o - 1;
    if (yok) {
        for (int base = 0; base < 144; base += 8) {
            int ch = base + (t >> 5), x = t & 31;
            sm.tile[ch][x] = f2bf(x_hsi[(((size_t)b * 144 + ch) * 32 + iy) * 32 + x]);
        }
    }
    __syncthreads();
    short* dstb = xb2 + (size_t)b * XB_B;
    for (int item = t; item < 680; item += 256) {   // 20 cb x 34 xx, 16B each
        int cb = item / 34;
        int xx = item - cb * 34;
        bf16x8s v = {0, 0, 0, 0, 0, 0, 0, 0};
        if (yok && xx >= 1 && xx <= 32 && cb < 18) {
            int x = xx - 1;
            #pragma unroll
            for (int d = 0; d < 8; ++d) v[d] = sm.tile[cb * 8 + d][x];
        }
        *(bf16x8s*)(dstb + ((size_t)(cb * 34 + y_o) * 34 + xx) * 8) = v;
    }
}

// ---------------- k2: HSI conv via MFMA --------------------------------------
// 1024 blocks = b(64) x ytile(16). Stage padded rows y0..y0+3 x 34 x 160ch
// (43.6KB LDS, plane stride 1090 shorts ≡ 1 bank -> conflict-free reads).
// 4 waves = (2 rows x 2 x-halves); wave: 16 px x 32 oc, K = 9 taps x 160.
__global__ __launch_bounds__(256) void conv_hsi_kernel(
        const short* __restrict__ xb2, const short* __restrict__ wtb2,
        const float* __restrict__ bh, short* __restrict__ capsb) {
    __shared__ union {
        short xs[20 * PLANE_SH];   // 43600 B
        float ct[64][33];          // 8448 B
    } sm;
    int t = threadIdx.x;
    int b = blockIdx.x >> 4;
    int y0 = (blockIdx.x & 15) << 1;          // output rows y0, y0+1

    // ---- stage: pure bf16 copy, 16B/lane, 11 iterations ---------------------
    const short* src = xb2 + (size_t)b * XB_B + y0 * 272;   // + y0*34*8
    for (int i = t; i < 2720; i += 256) {     // 20 planes x 136 items
        int cb = i / 136;
        int rem = i - cb * 136;
        bf16x8s v = *(const bf16x8s*)(src + (size_t)cb * 9248 + rem * 8);
        *(bf16x8s*)&sm.xs[cb * PLANE_SH + rem * 8] = v;
    }
    __syncthreads();

    int l = t & 63;
    int wv = t >> 6;
    int wr = wv >> 1;            // output row within block
    int xh = wv & 1;             // x half
    int l15 = l & 15, lhi = l >> 4;

    f32x4 acc0 = {0.f, 0.f, 0.f, 0.f};
    f32x4 acc1 = {0.f, 0.f, 0.f, 0.f};

    #pragma unroll
    for (int tap = 0; tap < 9; ++tap) {
        int dy = tap / 3, dx = tap % 3;
        int arow = ((wr + dy) * 34 + xh * 16 + l15 + dx) * 8;
        #pragma unroll
        for (int kc = 0; kc < 5; ++kc) {
            bf16x8s a = *(const bf16x8s*)&sm.xs[(kc * 4 + lhi) * PLANE_SH + arow];
            const short* wa = wtb2 + ((size_t)(tap * 20 + kc * 4 + lhi) * 32 + l15) * 8;
            bf16x8s b0 = *(const bf16x8s*)wa;
            bf16x8s b1 = *(const bf16x8s*)(wa + 128);   // +16 oc
            acc0 = __builtin_amdgcn_mfma_f32_16x16x32_bf16(a, b0, acc0, 0, 0, 0);
            acc1 = __builtin_amdgcn_mfma_f32_16x16x32_bf16(a, b1, acc1, 0, 0, 0);
        }
    }
    __syncthreads();   // xs reads done before ct overwrites

    #pragma unroll
    for (int r = 0; r < 4; ++r) {
        int px = wr * 32 + xh * 16 + lhi * 4 + r;
        sm.ct[px][l15] = acc0[r];
        sm.ct[px][16 + l15] = acc1[r];
    }
    __syncthreads();

    // ---- epilogue: 256 capsules (64 px x 4 caps), 1 per thread --------------
    int p = t >> 2;              // local pixel 0..63
    int cap = t & 3;
    float s[8];
    float sq = 0.0f;
    #pragma unroll
    for (int d = 0; d < 8; ++d) {
        s[d] = sm.ct[p][cap * 8 + d] + bh[cap * 8 + d];
        sq += s[d] * s[d];
    }
    float scale = sq / ((1.0f + sq) * sqrtf(sq + 1e-8f));
    int pix = (y0 + (p >> 5)) * 32 + (p & 31);
    int n = pix * 4 + cap;
    bf16x8s o;
    #pragma unroll
    for (int d = 0; d < 8; ++d) o[d] = f2bf(s[d] * scale);
    *(bf16x8s*)(capsb + ((size_t)b * 8192 + n) * 8) = o;
}

// ---------------- k3: routing via MFMA ---------------------------------------
// grid (kc 256) x (ntp 5). Block: stage caps[b][kc*32 .. +32] -> LDS [n][b][8]
// (transpose on write), 8 K-steps (2 per wave), 2 cj-tiles per block.
__global__ __launch_bounds__(256) void routing_mfma_kernel(
        const short* __restrict__ capsb, const float* __restrict__ W,
        float* __restrict__ partials) {
    __shared__ union {
        short ct[32][64][8];    // [n_local][b][8] = 32768 B
        float red[4][64][32];   // cross-wave reduce = 32768 B
    } sm;
    int t = threadIdx.x;
    int kc = blockIdx.x;
    int ntp = blockIdx.y;
    int n0 = kc * 32;

    {   // stage: thread t: b = t>>2, ng = t&3; 8x contiguous 16B global reads
        int b = t >> 2;
        int ng = t & 3;
        const short* src = capsb + ((size_t)b * 8192 + n0 + ng * 8) * 8;
        #pragma unroll
        for (int i = 0; i < 8; ++i) {
            bf16x8s v = *(const bf16x8s*)(src + i * 8);
            *(bf16x8s*)&sm.ct[ng * 8 + i][b][0] = v;
        }
    }
    __syncthreads();

    int l = t & 63;
    int wv = t >> 6;
    int l15 = l & 15, lhi = l >> 4;

    f32x4 acc[2][4];
    #pragma unroll
    for (int a = 0; a < 2; ++a)
        #pragma unroll
        for (int m = 0; m < 4; ++m) acc[a][m] = (f32x4){0.f, 0.f, 0.f, 0.f};

    #pragma unroll
    for (int ks = 0; ks < 2; ++ks) {
        int nl = (wv * 2 + ks) * 4 + lhi;     // n_local 0..31
        int n = n0 + nl;
        const float* wp = W + ((size_t)n * 160 + ntp * 32 + l15) * 8;
        union { short s[8]; bf16x8s v; } bu[2];
        #pragma unroll
        for (int ntl = 0; ntl < 2; ++ntl) {
            const float* wq = wp + (size_t)ntl * 128;   // +16 cj
            float4 w0 = *(const float4*)wq;
            float4 w1 = *(const float4*)(wq + 4);
            bu[ntl].s[0] = f2bf(w0.x); bu[ntl].s[1] = f2bf(w0.y);
            bu[ntl].s[2] = f2bf(w0.z); bu[ntl].s[3] = f2bf(w0.w);
            bu[ntl].s[4] = f2bf(w1.x); bu[ntl].s[5] = f2bf(w1.y);
            bu[ntl].s[6] = f2bf(w1.z); bu[ntl].s[7] = f2bf(w1.w);
        }
        bf16x8s af[4];
        #pragma unroll
        for (int mt = 0; mt < 4; ++mt)
            af[mt] = *(const bf16x8s*)&sm.ct[nl][mt * 16 + l15][0];
        #pragma unroll
        for (int ntl = 0; ntl < 2; ++ntl)
            #pragma unroll
            for (int mt = 0; mt < 4; ++mt)
                acc[ntl][mt] = __builtin_amdgcn_mfma_f32_16x16x32_bf16(
                    af[mt], bu[ntl].v, acc[ntl][mt], 0, 0, 0);
    }
    __syncthreads();   // all ct reads done before red overwrites

    #pragma unroll
    for (int ntl = 0; ntl < 2; ++ntl)
        #pragma unroll
        for (int mt = 0; mt < 4; ++mt)
            #pragma unroll
            for (int r = 0; r < 4; ++r)
                sm.red[wv][mt * 16 + lhi * 4 + r][ntl * 16 + l15] = acc[ntl][mt][r];
    __syncthreads();

    for (int idx = t; idx < 2048; idx += 256) {
        int b = idx >> 5, cjl = idx & 31;
        float sum = sm.red[0][b][cjl] + sm.red[1][b][cjl]
                  + sm.red[2][b][cjl] + sm.red[3][b][cjl];
        partials[(((size_t)kc * 5 + ntp) * 64 + b) * 32 + cjl] = sum;
    }
}

// ---------------- k4: final reduce + squash + norm ---------------------------
__global__ __launch_bounds__(256) void finalize_kernel(
        const float* __restrict__ partials, float* __restrict__ out) {
    __shared__ float s_sh[160];
    int t = threadIdx.x;
    int b = blockIdx.x;
    if (t < 160) {
        int ntp = t >> 5, cjl = t & 31;
        float s = 0.0f;
        #pragma unroll 8
        for (int kc = 0; kc < 256; ++kc)
            s += partials[(((size_t)kc * 5 + ntp) * 64 + b) * 32 + cjl];
        s_sh[ntp * 32 + cjl] = s * (1.0f / 8192.0f);
    }
    __syncthreads();
    if (t < 10) {
        float sq = 0.0f;
        #pragma unroll
        for (int j = 0; j < 16; ++j) {
            float v = s_sh[t * 16 + j];
            sq += v * v;
        }
        float scale = sq / ((1.0f + sq) * sqrtf(sq + 1e-8f));
        out[b * 10 + t] = sqrtf(sq) * scale;
    }
}

extern "C" void kernel_launch(void* const* d_in, const int* in_sizes, int n_in,
                              void* d_out, int out_size, void* d_ws, size_t ws_size,
                              hipStream_t stream) {
    const float* x_hsi = (const float*)d_in[0];   // [64,144,32,32]
    const float* x_sar = (const float*)d_in[1];   // [64,4,32,32]
    const float* wh    = (const float*)d_in[2];   // [32,144,3,3]
    const float* bh    = (const float*)d_in[3];   // [32]
    const float* wsar  = (const float*)d_in[4];   // [32,4,3,3]
    const float* bs    = (const float*)d_in[5];   // [32]
    const float* W     = (const float*)d_in[6];   // [8192,10,16,8]
    float* out = (float*)d_out;                   // [64,10]

    char* ws = (char*)d_ws;
    short* wtb2     = (short*)(ws + 0);           // 9*20*32*8*2 = 92160 B
    short* xb2      = (short*)(ws + 131072);      // 64*20*34*34*8*2 = 23674880 B
    // partials aliases xb2 (xb2 dead once conv_hsi completes; same-stream order)
    float* partials = (float*)(ws + 131072);      // 256*5*64*32*4 = 10485760 B
    short* capsb    = (short*)(ws + 23805952);    // [64][8192][8] bf16 = 8388608 B

    prep_kernel<<<2612, 256, 0, stream>>>(wh, wtb2, x_hsi, xb2, x_sar, wsar, bs, capsb);

    conv_hsi_kernel<<<1024, 256, 0, stream>>>(xb2, wtb2, bh, capsb);

    routing_mfma_kernel<<<dim3(256, 5), 256, 0, stream>>>(capsb, W, partials);

    finalize_kernel<<<64, 256, 0, stream>>>(partials, out);
}

// Round 11
// 70.110 us; speedup vs baseline: 1.1247x; 1.0955x over previous
//
#include <hip/hip_runtime.h>
#include <hip/hip_bf16.h>

// FastCapsNetMulti via bf16 MFMA, 4 launches:
//  k1 prep: blocks 0..179    wh   -> wtb2[tap][cb20][oc32][8] bf16
//           blocks 180..2355 x_hsi-> xb2[b][cb20][y34][x34][8] bf16 (zero-padded)
//           blocks 2356..2611 SAR conv (weights transposed to LDS, thread=pixel)
//  k2 conv_hsi: 1024 blocks = b(64) x ytile(16, 2 output rows). Stage 4 padded
//               rows into LDS; PLANE_SH=1096 shorts (2192B, 16B-aligned -> true
//               ds_read_b128; stride ≡ 4 banks -> 8-dword/bank floor).
//               45 MFMA steps, B direct from global (L2), squash -> capsb[b][n][8]
//  k3 routing: s[b,cj] = sum caps*W; 64-n chunks LDS-transposed, W fp32->bf16 inline
//  k4 finalize: reduce + squash + |v|
// B=64, H=W=32, N=8192, classes=10, class_dim=16, cap_dim=8.

typedef __attribute__((ext_vector_type(8))) short bf16x8s;
typedef __attribute__((ext_vector_type(4))) float f32x4;

__device__ inline short f2bf(float f) {
    __hip_bfloat16 h = __float2bfloat16(f);
    return *reinterpret_cast<short*>(&h);
}

#define XB_B (20 * 1156 * 8)   // elements per b in xb2 ([cb][34][34][8])
#define PLANE_SH 1096          // 4*34*8 + 8 pad: 16B-aligned stride, ≡4 banks

// ---------------- k1: prep (weights + activations + SAR conv) ----------------
__global__ __launch_bounds__(256) void prep_kernel(
        const float* __restrict__ wh, short* __restrict__ wtb2,
        const float* __restrict__ x_hsi, short* __restrict__ xb2,
        const float* __restrict__ x_sar, const float* __restrict__ wsar,
        const float* __restrict__ bs, short* __restrict__ capsb) {
    __shared__ union {
        short tile[144][33];    // x-pass transpose
        float wt_lds[1152];     // SAR weights [cin][tap][oc]
    } sm;
    int t = threadIdx.x;

    if (blockIdx.x < 180) {
        // wtb2[tap][cb][oc][d]
        int idx = blockIdx.x * 256 + t;       // < 9*20*32*8 = 46080
        int tap = idx / 5120;
        int r2 = idx - tap * 5120;
        int cb = r2 >> 8;
        int oc = (r2 >> 3) & 31;
        int d = r2 & 7;
        int ch = cb * 8 + d;
        short v = 0;
        if (ch < 144) v = f2bf(wh[(oc * 144 + ch) * 9 + tap]);
        wtb2[idx] = v;
        return;
    }

    if (blockIdx.x >= 2356) {
        // ---- SAR conv: stage transposed weights to LDS, thread = 1 pixel ----
        for (int i = t; i < 1152; i += 256) {
            int oc = i / 36;
            int r = i - oc * 36;
            int cin = r / 9;
            int tap = r - cin * 9;
            sm.wt_lds[cin * 288 + tap * 32 + oc] = wsar[i];
        }
        __syncthreads();

        int px_global = (blockIdx.x - 2356) * 256 + t;   // 0..65535
        int b = px_global >> 10;
        int p = px_global & 1023;
        int y = p >> 5, x = p & 31;

        float acc[32];
        #pragma unroll
        for (int oc = 0; oc < 32; ++oc) acc[oc] = bs[oc];

        for (int cin = 0; cin < 4; ++cin) {
            const float* xc = x_sar + ((size_t)b * 4 + cin) * 1024;
            const float* wc = &sm.wt_lds[cin * 288];
            #pragma unroll
            for (int ky = 0; ky < 3; ++ky) {
                int iy = y + ky - 1;
                bool rowok = (iy >= 0) && (iy < 32);
                const float* xrow = xc + iy * 32;
                float v0 = (rowok && x > 0)  ? xrow[x - 1] : 0.0f;
                float v1 = rowok             ? xrow[x]     : 0.0f;
                float v2 = (rowok && x < 31) ? xrow[x + 1] : 0.0f;
                const float* wk = wc + ky * 96;
                #pragma unroll
                for (int oc = 0; oc < 32; ++oc)
                    acc[oc] += v0 * wk[oc] + v1 * wk[32 + oc] + v2 * wk[64 + oc];
            }
        }

        #pragma unroll
        for (int cap = 0; cap < 4; ++cap) {
            float sq = 0.0f;
            #pragma unroll
            for (int d = 0; d < 8; ++d) sq += acc[cap * 8 + d] * acc[cap * 8 + d];
            float scale = sq / ((1.0f + sq) * sqrtf(sq + 1e-8f));
            int n = 4096 + p * 4 + cap;
            bf16x8s o;
            #pragma unroll
            for (int d = 0; d < 8; ++d) o[d] = f2bf(acc[cap * 8 + d] * scale);
            *(bf16x8s*)(capsb + ((size_t)b * 8192 + n) * 8) = o;
        }
        return;
    }

    // ---- x-pass: one block per (b, padded row y_o); LDS transpose ----------
    int blk = blockIdx.x - 180;               // 0..2175
    int b = blk / 34;
    int y_o = blk - b * 34;
    bool yok = (y_o >= 1) && (y_o <= 32);
    int iy = y_o - 1;
    if (yok) {
        for (int base = 0; base < 144; base += 8) {
            int ch = base + (t >> 5), x = t & 31;
            sm.tile[ch][x] = f2bf(x_hsi[(((size_t)b * 144 + ch) * 32 + iy) * 32 + x]);
        }
    }
    __syncthreads();
    short* dstb = xb2 + (size_t)b * XB_B;
    for (int item = t; item < 680; item += 256) {   // 20 cb x 34 xx, 16B each
        int cb = item / 34;
        int xx = item - cb * 34;
        bf16x8s v = {0, 0, 0, 0, 0, 0, 0, 0};
        if (yok && xx >= 1 && xx <= 32 && cb < 18) {
            int x = xx - 1;
            #pragma unroll
            for (int d = 0; d < 8; ++d) v[d] = sm.tile[cb * 8 + d][x];
        }
        *(bf16x8s*)(dstb + ((size_t)(cb * 34 + y_o) * 34 + xx) * 8) = v;
    }
}

// ---------------- k2: HSI conv via MFMA --------------------------------------
// 1024 blocks = b(64) x ytile(16). Stage padded rows y0..y0+3 x 34 x 160ch
// (43.8KB LDS, plane stride 1096 shorts = 2192B: 16B-aligned -> ds_read_b128,
// ≡4 banks -> conflict floor). 4 waves = (2 rows x 2 x-halves);
// wave: 16 px x 32 oc, K = 9 taps x 160. B direct from global wtb2.
__global__ __launch_bounds__(256) void conv_hsi_kernel(
        const short* __restrict__ xb2, const short* __restrict__ wtb2,
        const float* __restrict__ bh, short* __restrict__ capsb) {
    __shared__ union {
        short xs[20 * PLANE_SH];   // 43840 B
        float ct[64][33];          // 8448 B
    } sm;
    int t = threadIdx.x;
    int b = blockIdx.x >> 4;
    int y0 = (blockIdx.x & 15) << 1;          // output rows y0, y0+1

    // ---- stage: pure bf16 copy, 16B/lane, 11 iterations ---------------------
    const short* src = xb2 + (size_t)b * XB_B + y0 * 272;   // + y0*34*8
    for (int i = t; i < 2720; i += 256) {     // 20 planes x 136 items
        int cb = i / 136;
        int rem = i - cb * 136;
        bf16x8s v = *(const bf16x8s*)(src + (size_t)cb * 9248 + rem * 8);
        *(bf16x8s*)&sm.xs[cb * PLANE_SH + rem * 8] = v;
    }
    __syncthreads();

    int l = t & 63;
    int wv = t >> 6;
    int wr = wv >> 1;            // output row within block
    int xh = wv & 1;             // x half
    int l15 = l & 15, lhi = l >> 4;

    f32x4 acc0 = {0.f, 0.f, 0.f, 0.f};
    f32x4 acc1 = {0.f, 0.f, 0.f, 0.f};

    #pragma unroll
    for (int tap = 0; tap < 9; ++tap) {
        int dy = tap / 3, dx = tap % 3;
        int arow = ((wr + dy) * 34 + xh * 16 + l15 + dx) * 8;
        #pragma unroll
        for (int kc = 0; kc < 5; ++kc) {
            int plane = kc * 4 + lhi;
            bf16x8s a = *(const bf16x8s*)&sm.xs[plane * PLANE_SH + arow];
            const short* wa = wtb2 + ((size_t)(tap * 20 + plane) * 32 + l15) * 8;
            bf16x8s b0 = *(const bf16x8s*)wa;
            bf16x8s b1 = *(const bf16x8s*)(wa + 128);   // +16 oc
            acc0 = __builtin_amdgcn_mfma_f32_16x16x32_bf16(a, b0, acc0, 0, 0, 0);
            acc1 = __builtin_amdgcn_mfma_f32_16x16x32_bf16(a, b1, acc1, 0, 0, 0);
        }
    }
    __syncthreads();   // xs reads done before ct overwrites

    #pragma unroll
    for (int r = 0; r < 4; ++r) {
        int px = wr * 32 + xh * 16 + lhi * 4 + r;
        sm.ct[px][l15] = acc0[r];
        sm.ct[px][16 + l15] = acc1[r];
    }
    __syncthreads();

    // ---- epilogue: 256 capsules (64 px x 4 caps), 1 per thread --------------
    int p = t >> 2;              // local pixel 0..63
    int cap = t & 3;
    float s[8];
    float sq = 0.0f;
    #pragma unroll
    for (int d = 0; d < 8; ++d) {
        s[d] = sm.ct[p][cap * 8 + d] + bh[cap * 8 + d];
        sq += s[d] * s[d];
    }
    float scale = sq / ((1.0f + sq) * sqrtf(sq + 1e-8f));
    int pix = (y0 + (p >> 5)) * 32 + (p & 31);
    int n = pix * 4 + cap;
    bf16x8s o;
    #pragma unroll
    for (int d = 0; d < 8; ++d) o[d] = f2bf(s[d] * scale);
    *(bf16x8s*)(capsb + ((size_t)b * 8192 + n) * 8) = o;
}

// ---------------- k3: routing via MFMA ---------------------------------------
// grid (kc 128) x (ntp 5). Block: stage caps[b][kc*64 .. +64] -> LDS [n][b][8]
// (transpose on write), 16 K-steps (4 per wave), 2 cj-tiles per block.
__global__ __launch_bounds__(256) void routing_mfma_kernel(
        const short* __restrict__ capsb, const float* __restrict__ W,
        float* __restrict__ partials) {
    __shared__ union {
        short ct[64][64][8];    // [n_local][b][8] = 65536 B
        float red[4][64][34];   // cross-wave reduce (34-pad)
    } sm;
    int t = threadIdx.x;
    int kc = blockIdx.x;
    int ntp = blockIdx.y;
    int n0 = kc * 64;

    {   // stage: thread t: b = t>>2, ng = t&3; 16x contiguous 16B global reads
        int b = t >> 2;
        int ng = t & 3;
        const short* src = capsb + ((size_t)b * 8192 + n0 + ng * 16) * 8;
        #pragma unroll
        for (int i = 0; i < 16; ++i) {
            bf16x8s v = *(const bf16x8s*)(src + i * 8);
            *(bf16x8s*)&sm.ct[ng * 16 + i][b][0] = v;
        }
    }
    __syncthreads();

    int l = t & 63;
    int wv = t >> 6;
    int l15 = l & 15, lhi = l >> 4;

    f32x4 acc[2][4];
    #pragma unroll
    for (int a = 0; a < 2; ++a)
        #pragma unroll
        for (int m = 0; m < 4; ++m) acc[a][m] = (f32x4){0.f, 0.f, 0.f, 0.f};

    #pragma unroll
    for (int ks = 0; ks < 4; ++ks) {
        int nl = (wv * 4 + ks) * 4 + lhi;     // n_local 0..63
        int n = n0 + nl;
        const float* wp = W + ((size_t)n * 160 + ntp * 32 + l15) * 8;
        union { short s[8]; bf16x8s v; } bu[2];
        #pragma unroll
        for (int ntl = 0; ntl < 2; ++ntl) {
            const float* wq = wp + (size_t)ntl * 128;   // +16 cj
            float4 w0 = *(const float4*)wq;
            float4 w1 = *(const float4*)(wq + 4);
            bu[ntl].s[0] = f2bf(w0.x); bu[ntl].s[1] = f2bf(w0.y);
            bu[ntl].s[2] = f2bf(w0.z); bu[ntl].s[3] = f2bf(w0.w);
            bu[ntl].s[4] = f2bf(w1.x); bu[ntl].s[5] = f2bf(w1.y);
            bu[ntl].s[6] = f2bf(w1.z); bu[ntl].s[7] = f2bf(w1.w);
        }
        bf16x8s af[4];
        #pragma unroll
        for (int mt = 0; mt < 4; ++mt)
            af[mt] = *(const bf16x8s*)&sm.ct[nl][mt * 16 + l15][0];
        #pragma unroll
        for (int ntl = 0; ntl < 2; ++ntl)
            #pragma unroll
            for (int mt = 0; mt < 4; ++mt)
                acc[ntl][mt] = __builtin_amdgcn_mfma_f32_16x16x32_bf16(
                    af[mt], bu[ntl].v, acc[ntl][mt], 0, 0, 0);
    }
    __syncthreads();   // all ct reads done before red overwrites

    #pragma unroll
    for (int ntl = 0; ntl < 2; ++ntl)
        #pragma unroll
        for (int mt = 0; mt < 4; ++mt)
            #pragma unroll
            for (int r = 0; r < 4; ++r)
                sm.red[wv][mt * 16 + lhi * 4 + r][ntl * 16 + l15] = acc[ntl][mt][r];
    __syncthreads();

    for (int idx = t; idx < 2048; idx += 256) {
        int b = idx >> 5, cjl = idx & 31;
        float sum = sm.red[0][b][cjl] + sm.red[1][b][cjl]
                  + sm.red[2][b][cjl] + sm.red[3][b][cjl];
        partials[(((size_t)kc * 5 + ntp) * 64 + b) * 32 + cjl] = sum;
    }
}

// ---------------- k4: final reduce + squash + norm ---------------------------
__global__ __launch_bounds__(256) void finalize_kernel(
        const float* __restrict__ partials, float* __restrict__ out) {
    __shared__ float s_sh[160];
    int t = threadIdx.x;
    int b = blockIdx.x;
    if (t < 160) {
        int ntp = t >> 5, cjl = t & 31;
        float s = 0.0f;
        #pragma unroll 8
        for (int kc = 0; kc < 128; ++kc)
            s += partials[(((size_t)kc * 5 + ntp) * 64 + b) * 32 + cjl];
        s_sh[ntp * 32 + cjl] = s * (1.0f / 8192.0f);
    }
    __syncthreads();
    if (t < 10) {
        float sq = 0.0f;
        #pragma unroll
        for (int j = 0; j < 16; ++j) {
            float v = s_sh[t * 16 + j];
            sq += v * v;
        }
        float scale = sq / ((1.0f + sq) * sqrtf(sq + 1e-8f));
        out[b * 10 + t] = sqrtf(sq) * scale;
    }
}

extern "C" void kernel_launch(void* const* d_in, const int* in_sizes, int n_in,
                              void* d_out, int out_size, void* d_ws, size_t ws_size,
                              hipStream_t stream) {
    const float* x_hsi = (const float*)d_in[0];   // [64,144,32,32]
    const float* x_sar = (const float*)d_in[1];   // [64,4,32,32]
    const float* wh    = (const float*)d_in[2];   // [32,144,3,3]
    const float* bh    = (const float*)d_in[3];   // [32]
    const float* wsar  = (const float*)d_in[4];   // [32,4,3,3]
    const float* bs    = (const float*)d_in[5];   // [32]
    const float* W     = (const float*)d_in[6];   // [8192,10,16,8]
    float* out = (float*)d_out;                   // [64,10]

    char* ws = (char*)d_ws;
    short* wtb2     = (short*)(ws + 0);           // 9*20*32*8*2 = 92160 B
    short* xb2      = (short*)(ws + 131072);      // 64*20*34*34*8*2 = 23674880 B
    // partials aliases xb2 (xb2 dead once conv_hsi completes; same-stream order)
    float* partials = (float*)(ws + 131072);      // 128*5*64*32*4 = 5242880 B
    short* capsb    = (short*)(ws + 23805952);    // [64][8192][8] bf16 = 8388608 B

    prep_kernel<<<2612, 256, 0, stream>>>(wh, wtb2, x_hsi, xb2, x_sar, wsar, bs, capsb);

    conv_hsi_kernel<<<1024, 256, 0, stream>>>(xb2, wtb2, bh, capsb);

    routing_mfma_kernel<<<dim3(128, 5), 256, 0, stream>>>(capsb, W, partials);

    finalize_kernel<<<64, 256, 0, stream>>>(partials, out);
}

// Round 12
// 69.040 us; speedup vs baseline: 1.1422x; 1.0155x over previous
//
#include <hip/hip_runtime.h>
#include <hip/hip_bf16.h>

// FastCapsNetMulti via bf16 MFMA, 4 launches.
// This round's single change vs r11: XCD-aware bijective block swizzles so all
// blocks sharing one batch-index b land on ONE XCD (kills cross-XCD L2
// re-fetch amplification of xb2 / x_hsi / x_sar slices).
//  k1 prep: blocks 0..179    wh   -> wtb2[tap][cb20][oc32][8] bf16
//           blocks 180..2355 x_hsi-> xb2[b][cb20][y34][x34][8] bf16 (XCD-swizzled)
//           blocks 2356..2611 SAR conv (XCD-swizzled)
//  k2 conv_hsi: 1024 blocks, xcd=bid&7, b = xcd + 8*(slot>>4), yt = slot&15
//  k3 routing: grid(128,5) — kc%8 already pins all 5 ntp to one XCD
//  k4 finalize
// B=64, H=W=32, N=8192, classes=10, class_dim=16, cap_dim=8.

typedef __attribute__((ext_vector_type(8))) short bf16x8s;
typedef __attribute__((ext_vector_type(4))) float f32x4;

__device__ inline short f2bf(float f) {
    __hip_bfloat16 h = __float2bfloat16(f);
    return *reinterpret_cast<short*>(&h);
}

#define XB_B (20 * 1156 * 8)   // elements per b in xb2 ([cb][34][34][8])
#define PLANE_SH 1096          // 4*34*8 + 8 pad: 16B-aligned stride, ≡4 banks

// ---------------- k1: prep (weights + activations + SAR conv) ----------------
__global__ __launch_bounds__(256) void prep_kernel(
        const float* __restrict__ wh, short* __restrict__ wtb2,
        const float* __restrict__ x_hsi, short* __restrict__ xb2,
        const float* __restrict__ x_sar, const float* __restrict__ wsar,
        const float* __restrict__ bs, short* __restrict__ capsb) {
    __shared__ union {
        short tile[144][33];    // x-pass transpose
        float wt_lds[1152];     // SAR weights [cin][tap][oc]
    } sm;
    int t = threadIdx.x;

    if (blockIdx.x < 180) {
        // wtb2[tap][cb][oc][d]
        int idx = blockIdx.x * 256 + t;       // < 9*20*32*8 = 46080
        int tap = idx / 5120;
        int r2 = idx - tap * 5120;
        int cb = r2 >> 8;
        int oc = (r2 >> 3) & 31;
        int d = r2 & 7;
        int ch = cb * 8 + d;
        short v = 0;
        if (ch < 144) v = f2bf(wh[(oc * 144 + ch) * 9 + tap]);
        wtb2[idx] = v;
        return;
    }

    if (blockIdx.x >= 2356) {
        // ---- SAR conv: XCD-swizzled (256 = 8 xcd x 32 slots) ----------------
        for (int i = t; i < 1152; i += 256) {
            int oc = i / 36;
            int r = i - oc * 36;
            int cin = r / 9;
            int tap = r - cin * 9;
            sm.wt_lds[cin * 288 + tap * 32 + oc] = wsar[i];
        }
        __syncthreads();

        int blk = blockIdx.x - 2356;          // 0..255
        int xcd = blk & 7;
        int slot = blk >> 3;                  // 0..31
        int b = xcd + ((slot >> 2) << 3);     // all 4 quarters of b on one XCD
        int q = slot & 3;
        int p = q * 256 + t;                  // pixel 0..1023
        int y = p >> 5, x = p & 31;

        float acc[32];
        #pragma unroll
        for (int oc = 0; oc < 32; ++oc) acc[oc] = bs[oc];

        for (int cin = 0; cin < 4; ++cin) {
            const float* xc = x_sar + ((size_t)b * 4 + cin) * 1024;
            const float* wc = &sm.wt_lds[cin * 288];
            #pragma unroll
            for (int ky = 0; ky < 3; ++ky) {
                int iy = y + ky - 1;
                bool rowok = (iy >= 0) && (iy < 32);
                const float* xrow = xc + iy * 32;
                float v0 = (rowok && x > 0)  ? xrow[x - 1] : 0.0f;
                float v1 = rowok             ? xrow[x]     : 0.0f;
                float v2 = (rowok && x < 31) ? xrow[x + 1] : 0.0f;
                const float* wk = wc + ky * 96;
                #pragma unroll
                for (int oc = 0; oc < 32; ++oc)
                    acc[oc] += v0 * wk[oc] + v1 * wk[32 + oc] + v2 * wk[64 + oc];
            }
        }

        #pragma unroll
        for (int cap = 0; cap < 4; ++cap) {
            float sq = 0.0f;
            #pragma unroll
            for (int d = 0; d < 8; ++d) sq += acc[cap * 8 + d] * acc[cap * 8 + d];
            float scale = sq / ((1.0f + sq) * sqrtf(sq + 1e-8f));
            int n = 4096 + p * 4 + cap;
            bf16x8s o;
            #pragma unroll
            for (int d = 0; d < 8; ++d) o[d] = f2bf(acc[cap * 8 + d] * scale);
            *(bf16x8s*)(capsb + ((size_t)b * 8192 + n) * 8) = o;
        }
        return;
    }

    // ---- x-pass: XCD-swizzled (2176 = 8 xcd x 272 slots, 272 = 8 b x 34 y) --
    int blk = blockIdx.x - 180;               // 0..2175
    int xcd = blk & 7;
    int slot = blk >> 3;                      // 0..271
    int b = xcd + ((slot / 34) << 3);         // all 34 rows of b on one XCD
    int y_o = slot % 34;
    bool yok = (y_o >= 1) && (y_o <= 32);
    int iy = y_o - 1;
    if (yok) {
        for (int base = 0; base < 144; base += 8) {
            int ch = base + (t >> 5), x = t & 31;
            sm.tile[ch][x] = f2bf(x_hsi[(((size_t)b * 144 + ch) * 32 + iy) * 32 + x]);
        }
    }
    __syncthreads();
    short* dstb = xb2 + (size_t)b * XB_B;
    for (int item = t; item < 680; item += 256) {   // 20 cb x 34 xx, 16B each
        int cb = item / 34;
        int xx = item - cb * 34;
        bf16x8s v = {0, 0, 0, 0, 0, 0, 0, 0};
        if (yok && xx >= 1 && xx <= 32 && cb < 18) {
            int x = xx - 1;
            #pragma unroll
            for (int d = 0; d < 8; ++d) v[d] = sm.tile[cb * 8 + d][x];
        }
        *(bf16x8s*)(dstb + ((size_t)(cb * 34 + y_o) * 34 + xx) * 8) = v;
    }
}

// ---------------- k2: HSI conv via MFMA --------------------------------------
// 1024 blocks XCD-swizzled: xcd=bid&7, slot=bid>>3 (0..127),
// b = xcd + 8*(slot>>4), ytile = slot&15 -> each b's xb2 slice (370KB) is
// fetched by exactly one XCD's L2 (16 blocks, row-overlap = L2 hits).
__global__ __launch_bounds__(256) void conv_hsi_kernel(
        const short* __restrict__ xb2, const short* __restrict__ wtb2,
        const float* __restrict__ bh, short* __restrict__ capsb) {
    __shared__ union {
        short xs[20 * PLANE_SH];   // 43840 B
        float ct[64][33];          // 8448 B
    } sm;
    int t = threadIdx.x;
    int bid = blockIdx.x;
    int xcd = bid & 7;
    int slot = bid >> 3;                      // 0..127
    int b = xcd + ((slot >> 4) << 3);
    int y0 = (slot & 15) << 1;                // output rows y0, y0+1

    // ---- stage: pure bf16 copy, 16B/lane, 11 iterations ---------------------
    const short* src = xb2 + (size_t)b * XB_B + y0 * 272;   // + y0*34*8
    for (int i = t; i < 2720; i += 256) {     // 20 planes x 136 items
        int cb = i / 136;
        int rem = i - cb * 136;
        bf16x8s v = *(const bf16x8s*)(src + (size_t)cb * 9248 + rem * 8);
        *(bf16x8s*)&sm.xs[cb * PLANE_SH + rem * 8] = v;
    }
    __syncthreads();

    int l = t & 63;
    int wv = t >> 6;
    int wr = wv >> 1;            // output row within block
    int xh = wv & 1;             // x half
    int l15 = l & 15, lhi = l >> 4;

    f32x4 acc0 = {0.f, 0.f, 0.f, 0.f};
    f32x4 acc1 = {0.f, 0.f, 0.f, 0.f};

    #pragma unroll
    for (int tap = 0; tap < 9; ++tap) {
        int dy = tap / 3, dx = tap % 3;
        int arow = ((wr + dy) * 34 + xh * 16 + l15 + dx) * 8;
        #pragma unroll
        for (int kc = 0; kc < 5; ++kc) {
            int plane = kc * 4 + lhi;
            bf16x8s a = *(const bf16x8s*)&sm.xs[plane * PLANE_SH + arow];
            const short* wa = wtb2 + ((size_t)(tap * 20 + plane) * 32 + l15) * 8;
            bf16x8s b0 = *(const bf16x8s*)wa;
            bf16x8s b1 = *(const bf16x8s*)(wa + 128);   // +16 oc
            acc0 = __builtin_amdgcn_mfma_f32_16x16x32_bf16(a, b0, acc0, 0, 0, 0);
            acc1 = __builtin_amdgcn_mfma_f32_16x16x32_bf16(a, b1, acc1, 0, 0, 0);
        }
    }
    __syncthreads();   // xs reads done before ct overwrites

    #pragma unroll
    for (int r = 0; r < 4; ++r) {
        int px = wr * 32 + xh * 16 + lhi * 4 + r;
        sm.ct[px][l15] = acc0[r];
        sm.ct[px][16 + l15] = acc1[r];
    }
    __syncthreads();

    // ---- epilogue: 256 capsules (64 px x 4 caps), 1 per thread --------------
    int p = t >> 2;              // local pixel 0..63
    int cap = t & 3;
    float s[8];
    float sq = 0.0f;
    #pragma unroll
    for (int d = 0; d < 8; ++d) {
        s[d] = sm.ct[p][cap * 8 + d] + bh[cap * 8 + d];
        sq += s[d] * s[d];
    }
    float scale = sq / ((1.0f + sq) * sqrtf(sq + 1e-8f));
    int pix = (y0 + (p >> 5)) * 32 + (p & 31);
    int n = pix * 4 + cap;
    bf16x8s o;
    #pragma unroll
    for (int d = 0; d < 8; ++d) o[d] = f2bf(s[d] * scale);
    *(bf16x8s*)(capsb + ((size_t)b * 8192 + n) * 8) = o;
}

// ---------------- k3: routing via MFMA ---------------------------------------
// grid (kc 128) x (ntp 5): 128%8==0 -> all 5 ntp of one kc share an XCD (L2-hot
// caps re-read). Stage caps[b][kc*64 .. +64] -> LDS [n][b][8], 16 K-steps.
__global__ __launch_bounds__(256) void routing_mfma_kernel(
        const short* __restrict__ capsb, const float* __restrict__ W,
        float* __restrict__ partials) {
    __shared__ union {
        short ct[64][64][8];    // [n_local][b][8] = 65536 B
        float red[4][64][34];   // cross-wave reduce (34-pad)
    } sm;
    int t = threadIdx.x;
    int kc = blockIdx.x;
    int ntp = blockIdx.y;
    int n0 = kc * 64;

    {   // stage: thread t: b = t>>2, ng = t&3; 16x contiguous 16B global reads
        int b = t >> 2;
        int ng = t & 3;
        const short* src = capsb + ((size_t)b * 8192 + n0 + ng * 16) * 8;
        #pragma unroll
        for (int i = 0; i < 16; ++i) {
            bf16x8s v = *(const bf16x8s*)(src + i * 8);
            *(bf16x8s*)&sm.ct[ng * 16 + i][b][0] = v;
        }
    }
    __syncthreads();

    int l = t & 63;
    int wv = t >> 6;
    int l15 = l & 15, lhi = l >> 4;

    f32x4 acc[2][4];
    #pragma unroll
    for (int a = 0; a < 2; ++a)
        #pragma unroll
        for (int m = 0; m < 4; ++m) acc[a][m] = (f32x4){0.f, 0.f, 0.f, 0.f};

    #pragma unroll
    for (int ks = 0; ks < 4; ++ks) {
        int nl = (wv * 4 + ks) * 4 + lhi;     // n_local 0..63
        int n = n0 + nl;
        const float* wp = W + ((size_t)n * 160 + ntp * 32 + l15) * 8;
        union { short s[8]; bf16x8s v; } bu[2];
        #pragma unroll
        for (int ntl = 0; ntl < 2; ++ntl) {
            const float* wq = wp + (size_t)ntl * 128;   // +16 cj
            float4 w0 = *(const float4*)wq;
            float4 w1 = *(const float4*)(wq + 4);
            bu[ntl].s[0] = f2bf(w0.x); bu[ntl].s[1] = f2bf(w0.y);
            bu[ntl].s[2] = f2bf(w0.z); bu[ntl].s[3] = f2bf(w0.w);
            bu[ntl].s[4] = f2bf(w1.x); bu[ntl].s[5] = f2bf(w1.y);
            bu[ntl].s[6] = f2bf(w1.z); bu[ntl].s[7] = f2bf(w1.w);
        }
        bf16x8s af[4];
        #pragma unroll
        for (int mt = 0; mt < 4; ++mt)
            af[mt] = *(const bf16x8s*)&sm.ct[nl][mt * 16 + l15][0];
        #pragma unroll
        for (int ntl = 0; ntl < 2; ++ntl)
            #pragma unroll
            for (int mt = 0; mt < 4; ++mt)
                acc[ntl][mt] = __builtin_amdgcn_mfma_f32_16x16x32_bf16(
                    af[mt], bu[ntl].v, acc[ntl][mt], 0, 0, 0);
    }
    __syncthreads();   // all ct reads done before red overwrites

    #pragma unroll
    for (int ntl = 0; ntl < 2; ++ntl)
        #pragma unroll
        for (int mt = 0; mt < 4; ++mt)
            #pragma unroll
            for (int r = 0; r < 4; ++r)
                sm.red[wv][mt * 16 + lhi * 4 + r][ntl * 16 + l15] = acc[ntl][mt][r];
    __syncthreads();

    for (int idx = t; idx < 2048; idx += 256) {
        int b = idx >> 5, cjl = idx & 31;
        float sum = sm.red[0][b][cjl] + sm.red[1][b][cjl]
                  + sm.red[2][b][cjl] + sm.red[3][b][cjl];
        partials[(((size_t)kc * 5 + ntp) * 64 + b) * 32 + cjl] = sum;
    }
}

// ---------------- k4: final reduce + squash + norm ---------------------------
__global__ __launch_bounds__(256) void finalize_kernel(
        const float* __restrict__ partials, float* __restrict__ out) {
    __shared__ float s_sh[160];
    int t = threadIdx.x;
    int b = blockIdx.x;
    if (t < 160) {
        int ntp = t >> 5, cjl = t & 31;
        float s = 0.0f;
        #pragma unroll 8
        for (int kc = 0; kc < 128; ++kc)
            s += partials[(((size_t)kc * 5 + ntp) * 64 + b) * 32 + cjl];
        s_sh[ntp * 32 + cjl] = s * (1.0f / 8192.0f);
    }
    __syncthreads();
    if (t < 10) {
        float sq = 0.0f;
        #pragma unroll
        for (int j = 0; j < 16; ++j) {
            float v = s_sh[t * 16 + j];
            sq += v * v;
        }
        float scale = sq / ((1.0f + sq) * sqrtf(sq + 1e-8f));
        out[b * 10 + t] = sqrtf(sq) * scale;
    }
}

extern "C" void kernel_launch(void* const* d_in, const int* in_sizes, int n_in,
                              void* d_out, int out_size, void* d_ws, size_t ws_size,
                              hipStream_t stream) {
    const float* x_hsi = (const float*)d_in[0];   // [64,144,32,32]
    const float* x_sar = (const float*)d_in[1];   // [64,4,32,32]
    const float* wh    = (const float*)d_in[2];   // [32,144,3,3]
    const float* bh    = (const float*)d_in[3];   // [32]
    const float* wsar  = (const float*)d_in[4];   // [32,4,3,3]
    const float* bs    = (const float*)d_in[5];   // [32]
    const float* W     = (const float*)d_in[6];   // [8192,10,16,8]
    float* out = (float*)d_out;                   // [64,10]

    char* ws = (char*)d_ws;
    short* wtb2     = (short*)(ws + 0);           // 9*20*32*8*2 = 92160 B
    short* xb2      = (short*)(ws + 131072);      // 64*20*34*34*8*2 = 23674880 B
    // partials aliases xb2 (xb2 dead once conv_hsi completes; same-stream order)
    float* partials = (float*)(ws + 131072);      // 128*5*64*32*4 = 5242880 B
    short* capsb    = (short*)(ws + 23805952);    // [64][8192][8] bf16 = 8388608 B

    prep_kernel<<<2612, 256, 0, stream>>>(wh, wtb2, x_hsi, xb2, x_sar, wsar, bs, capsb);

    conv_hsi_kernel<<<1024, 256, 0, stream>>>(xb2, wtb2, bh, capsb);

    routing_mfma_kernel<<<dim3(128, 5), 256, 0, stream>>>(capsb, W, partials);

    finalize_kernel<<<64, 256, 0, stream>>>(partials, out);
}